// Round 3
// baseline (107.187 us; speedup 1.0000x reference)
//
#include <hip/hip_runtime.h>
#include <hip/hip_bf16.h>
#include <cstdint>
#include <cstddef>

#define BN_EPS 1e-5f

typedef float f32x4_t __attribute__((ext_vector_type(4)));
typedef __bf16 bf16x8_t __attribute__((ext_vector_type(8)));

__device__ __forceinline__ unsigned short f2bf(float f) {
    __hip_bfloat16 h = __float2bfloat16(f);
    return __builtin_bit_cast(unsigned short, h);
}
__device__ __forceinline__ float bf2f(unsigned short u) {
    unsigned int v = ((unsigned int)u) << 16;
    return __builtin_bit_cast(float, v);
}

// async global->LDS, 16B/lane; LDS dest is wave-uniform base + lane*16.
__device__ __forceinline__ void gld_lds16(void* lds, const void* gp) {
#if __has_builtin(__builtin_amdgcn_global_load_lds)
    __builtin_amdgcn_global_load_lds(
        (const __attribute__((address_space(1))) unsigned int*)gp,
        (__attribute__((address_space(3))) unsigned int*)lds, 16, 0, 0);
#else
    *(uint4*)lds = *(const uint4*)gp;
#endif
}

// ---------------- ws layout ----------------
// escale : float [B][T][N]                65536 f
// bns    : float sum[64]+sumsq[64]        128 f
// rowsum : float [B][N]                   8192 f
// He2    : bf16  [4 part][B*N][64]        2097152 us (4 MB)
// kpb    : bf16  [512 col=t*64+o][64 c]   32768 us
// bmatT  : bf16  [B][512 col][N(m)]       4194304 us (8 MB)
//
// R0: G (16 MB) eliminated; k_gemm recomputes the Gaussian A-operand in regs.
// R1: og 4->2 merge in k_gemm (acc[2][16], grid 512, 2 blk/CU). -6.3 us.
// R2 (this round):
//  - k_gemm: double-buffered Bs + counted s_waitcnt vmcnt(4) + raw s_barrier
//    (T3-min / m139 pattern) -- next-tile DMA stays in flight across the
//    barrier; load latency hides under A-exp AND previous MFMA phase.
//  - k_fin/k_bn: XCD-matched block swizzle (data-b == blockIdx&7 == XCD).
//  - k_g: 16 rows/block (staging amortized 2x), grid 1152->640.
// NOTE (prior-session lesson): device-scope ticket-barrier fusion cost ~20 us;
// keep k_fin/k_bn as separate launches. BK=64 crosses VGPR cliff; keep BK=32.

// K1: blocks 0..511: rowsum, 16 rows/block.
//     blocks 512..639: repack k_tensor -> kpb bf16 [t*64+o][c]; zero bns.
__global__ __launch_bounds__(256) void k_g(const float* __restrict__ points,
                                           const float* __restrict__ ktens,
                                           float* __restrict__ rowsum,
                                           unsigned short* __restrict__ kpb,
                                           float* __restrict__ bns) {
    __shared__ float praw[3072];
    __shared__ float px[1024], py[1024], pz[1024], hq[1024];
    __shared__ float part[16][128];  // rowsum partials [row][col-octet]
    __shared__ float p2[16][32];

    const int tid = threadIdx.x;
    if (blockIdx.x >= 512) {              // pack branch (block-uniform)
        const int i = (blockIdx.x - 512) * 256 + tid;    // i = (t*64+o)*64 + c
        const int t = i >> 12, o = (i >> 6) & 63, c = i & 63;
        kpb[i] = f2bf(ktens[(o * 64 + c) * 8 + t]);
        if (blockIdx.x == 512 && tid < 128) bns[tid] = 0.f;
        return;
    }

    const int b  = blockIdx.x & 7;               // XCD swizzle
    const int n0 = (blockIdx.x >> 3) * 16;

    for (int i = tid; i < 3072; i += 256) praw[i] = points[b * 3072 + i];
    __syncthreads();
    for (int n = tid; n < 1024; n += 256) {
        float x = praw[n * 3], y = praw[n * 3 + 1], z = praw[n * 3 + 2];
        px[n] = x; py[n] = y; pz[n] = z;
        hq[n] = -0.5f * (x * x + y * y + z * z);
    }
    __syncthreads();

    const int rhalf = tid >> 7;                  // 0/1: which row of the pair
    const int c0 = (tid & 127) * 8;              // column octet
    float vx[8], vy[8], vz[8], vh[8];
    *(float4*)&vx[0] = *(const float4*)&px[c0];
    *(float4*)&vx[4] = *(const float4*)&px[c0 + 4];
    *(float4*)&vy[0] = *(const float4*)&py[c0];
    *(float4*)&vy[4] = *(const float4*)&py[c0 + 4];
    *(float4*)&vz[0] = *(const float4*)&pz[c0];
    *(float4*)&vz[4] = *(const float4*)&pz[c0 + 4];
    *(float4*)&vh[0] = *(const float4*)&hq[c0];
    *(float4*)&vh[4] = *(const float4*)&hq[c0 + 4];

    #pragma unroll
    for (int u = 0; u < 8; ++u) {
        const int rl = u * 2 + rhalf;            // 0..15
        const int row = n0 + rl;
        const float rx = px[row], ry = py[row], rz = pz[row], hr = hq[row];
        float ssum = 0.f;
        #pragma unroll
        for (int j = 0; j < 8; ++j)
            ssum += __expf(hr + vh[j] + rx * vx[j] + ry * vy[j] + rz * vz[j]);
        part[rl][tid & 127] = ssum;
    }
    __syncthreads();
    #pragma unroll
    for (int rep = 0; rep < 2; ++rep) {   // level 1: 128 -> 32 partials per row
        const int row = rep * 8 + (tid >> 5), c4l = (tid & 31) * 4;
        float4 p = *(const float4*)&part[row][c4l];
        p2[row][tid & 31] = p.x + p.y + p.z + p.w;
    }
    __syncthreads();
    if (tid < 16) {   // level 2: 16 thr finish their row
        float s = 0.f;
        #pragma unroll
        for (int q = 0; q < 8; ++q) {
            float4 v = *(const float4*)&p2[tid][q * 4];
            s += v.x + v.y + v.z + v.w;
        }
        rowsum[b * 1024 + n0 + tid] = s;
    }
}

// K2: MFMA prep GEMM: bmat[m][col] = (sfac[t,m]/rowsum[m]) * sum_c funcs[m,c]*kpb[col,c]
// grid 256 = b(8) x mt(8,128 rows) x ct(4,128 cols); 4 waves; K=64; also escale.
__global__ __launch_bounds__(256) void k_prep(const float* __restrict__ points,
                                              const float* __restrict__ trans,
                                              const float* __restrict__ funcs,
                                              const unsigned short* __restrict__ kpb,
                                              const float* __restrict__ rowsum,
                                              unsigned short* __restrict__ bmatT,
                                              float* __restrict__ escale) {
    __shared__ unsigned short Asm[128 * 72];   // [m][c] bf16, stride 72
    __shared__ unsigned short Bsm[128 * 72];   // [col][c] bf16, stride 72
    __shared__ float sfacl[256];               // [tloc(2)][m(128)]

    const int b  = blockIdx.x & 7;
    const int mt = (blockIdx.x >> 3) & 7;
    const int ct = blockIdx.x >> 6;            // 0..3 (t-pair)
    const int m0 = mt * 128;

    const int tid  = threadIdx.x;
    const int wave = tid >> 6, lane = tid & 63;
    const int wr = wave >> 1, wc = wave & 1;
    const int fr = lane & 15, quad = lane >> 4;

    // sfac + escale (global reads only; no LDS dependency)
    {
        const int tloc = tid >> 7, m = tid & 127;
        const int t = ct * 2 + tloc;
        const float tx = trans[b * 24 + t * 3], ty = trans[b * 24 + t * 3 + 1],
                    tz = trans[b * 24 + t * 3 + 2];
        const float* pp = &points[(size_t)(b * 1024 + m0 + m) * 3];
        const float ptd = pp[0] * tx + pp[1] * ty + pp[2] * tz;
        const float tsq = tx * tx + ty * ty + tz * tz;
        const float rsv = rowsum[b * 1024 + m0 + m];
        sfacl[tloc * 128 + m] = __expf(-ptd - 0.5f * tsq) / rsv;
        escale[(size_t)(b * 8 + t) * 1024 + m0 + m] = __expf(ptd);
    }
    // stage A: funcs fp32 -> bf16 LDS [m][c]
    #pragma unroll
    for (int rep = 0; rep < 2; ++rep) {
        const int m = rep * 64 + (tid >> 2);
        const int c16 = (tid & 3) * 16;
        const float* fp = &funcs[((size_t)(b * 1024) + m0 + m) * 64 + c16];
        float4 f0 = *(const float4*)fp, f1 = *(const float4*)(fp + 4);
        float4 f2 = *(const float4*)(fp + 8), f3 = *(const float4*)(fp + 12);
        uint4 p0, p1;
        p0.x = f2bf(f0.x) | ((unsigned)f2bf(f0.y) << 16);
        p0.y = f2bf(f0.z) | ((unsigned)f2bf(f0.w) << 16);
        p0.z = f2bf(f1.x) | ((unsigned)f2bf(f1.y) << 16);
        p0.w = f2bf(f1.z) | ((unsigned)f2bf(f1.w) << 16);
        p1.x = f2bf(f2.x) | ((unsigned)f2bf(f2.y) << 16);
        p1.y = f2bf(f2.z) | ((unsigned)f2bf(f2.w) << 16);
        p1.z = f2bf(f3.x) | ((unsigned)f2bf(f3.y) << 16);
        p1.w = f2bf(f3.z) | ((unsigned)f2bf(f3.w) << 16);
        *(uint4*)&Asm[m * 72 + c16] = p0;
        *(uint4*)&Asm[m * 72 + c16 + 8] = p1;
    }
    // stage B: kpb bf16 -> LDS [col][c]
    #pragma unroll
    for (int rep = 0; rep < 4; ++rep) {
        const int col = rep * 32 + (tid >> 3);
        const int c8 = (tid & 7) * 8;
        uint4 v = *(const uint4*)&kpb[(size_t)(ct * 128 + col) * 64 + c8];
        *(uint4*)&Bsm[col * 72 + c8] = v;
    }
    __syncthreads();

    f32x4_t acc[4][4];
    #pragma unroll
    for (int i = 0; i < 4; ++i)
        #pragma unroll
        for (int j = 0; j < 4; ++j) acc[i][j] = f32x4_t{0.f, 0.f, 0.f, 0.f};

    #pragma unroll
    for (int s = 0; s < 2; ++s) {
        uint4 afr[4], bfr[4];
        #pragma unroll
        for (int i = 0; i < 4; ++i)
            afr[i] = *(const uint4*)&Asm[(wr * 64 + i * 16 + fr) * 72 + s * 32 + quad * 8];
        #pragma unroll
        for (int j = 0; j < 4; ++j)
            bfr[j] = *(const uint4*)&Bsm[(wc * 64 + j * 16 + fr) * 72 + s * 32 + quad * 8];
        #pragma unroll
        for (int i = 0; i < 4; ++i)
            #pragma unroll
            for (int j = 0; j < 4; ++j)
                acc[i][j] = __builtin_amdgcn_mfma_f32_16x16x32_bf16(
                    __builtin_bit_cast(bf16x8_t, afr[i]),
                    __builtin_bit_cast(bf16x8_t, bfr[j]),
                    acc[i][j], 0, 0, 0);
    }

    // epilogue: scale and pack 4 consecutive m per lane -> bmatT[b][col][m]
    #pragma unroll
    for (int i = 0; i < 4; ++i) {
        #pragma unroll
        for (int j = 0; j < 4; ++j) {
            const int colg = ct * 128 + wc * 64 + j * 16 + fr;
            ushort4 pk;
            {
                const int mb = wr * 64 + i * 16 + quad * 4;
                pk.x = f2bf(acc[i][j][0] * sfacl[wc * 128 + mb + 0]);
                pk.y = f2bf(acc[i][j][1] * sfacl[wc * 128 + mb + 1]);
                pk.z = f2bf(acc[i][j][2] * sfacl[wc * 128 + mb + 2]);
                pk.w = f2bf(acc[i][j][3] * sfacl[wc * 128 + mb + 3]);
                *(ushort4*)&bmatT[(size_t)(b * 512 + colg) * 1024 + m0 + mb] = pk;
            }
        }
    }
}

// K3: FUSED Gaussian + bf16 GEMM, BK=32, og-pair merged, Bs double-buffered
// with counted vmcnt (R2). grid 512 = b(8) x rt(8) x [ogp(2) x kh(4)]; 4 waves;
// 128 rows x 256 cols. Next K-step's DMA stays in flight across the barrier:
// [stage next][A-exp][vmcnt(4); s_barrier][B-reads+MFMA][s_barrier].
__global__ __launch_bounds__(256, 2) void k_gemm(const float* __restrict__ points,
                                                 const unsigned short* __restrict__ bmatT,
                                                 const float* __restrict__ escale,
                                                 unsigned short* __restrict__ He2) {
    __shared__ unsigned short Bs[2][8192];  // 2 x [c'(256)=t*32+oo][k(32)], k-swizzled
    __shared__ float escT[1024];            // [t(8)][row(128)]
    __shared__ float4 mp[256];              // m-points: x,y,z,hq (4 KB)

    const int b  = blockIdx.x & 7;        // XCD swizzle
    const int rt = (blockIdx.x >> 3) & 7;
    const int z  = blockIdx.x >> 6;       // 0..7
    const int ogp = z & 1;                // channel half (32 ch)
    const int kh  = z >> 1;               // K quarter
    const int n0 = rt * 128;
    const int kb = kh * 256;

    const int tid  = threadIdx.x;
    const int wave = tid >> 6, lane = tid & 63;

    const unsigned short* gB = bmatT + (size_t)(b * 512 + ogp * 32) * 1024 + kb;

    const int r16 = lane >> 2;            // row within 16-seg
    const int kq  = lane & 3;             // dest 16B k-group
    const int gsw = kq ^ (r16 & 3);       // swizzled source k-group

    const int fr = lane & 15;             // fragment row part
    const int quad = lane >> 4;           // fragment k part
    const int swoff = (quad ^ (fr & 3)) << 4;   // swizzled frag byte offset
    const int row_base = wave * 32;       // this wave's 32 output rows

    // ---- prologue: vmem loads first (in-order retire keeps DMA unwaited) ----
    // row registers: this lane's 2 fixed A-rows
    float rx0, ry0, rz0, rh0, rx1, ry1, rz1, rh1;
    {
        const float* p0 = &points[(size_t)(b * 1024 + n0 + row_base + fr) * 3];
        rx0 = p0[0]; ry0 = p0[1]; rz0 = p0[2];
        rh0 = -0.5f * (rx0 * rx0 + ry0 * ry0 + rz0 * rz0);
        const float* p1 = &points[(size_t)(b * 1024 + n0 + row_base + 16 + fr) * 3];
        rx1 = p1[0]; ry1 = p1[1]; rz1 = p1[2];
        rh1 = -0.5f * (rx1 * rx1 + ry1 * ry1 + rz1 * rz1);
    }
    {   // stage escale [8t][128 rows] + m-points (ds_writes force waits on
        // their own loads only; buf0 DMA is issued after)
        const int t = tid >> 5, r4 = (tid & 31) * 4;
        float4 ev = *(const float4*)&escale[(size_t)(b * 8 + t) * 1024 + n0 + r4];
        const float* pp = &points[(size_t)(b * 1024 + kb + tid) * 3];
        const float x = pp[0], y = pp[1], zz = pp[2];
        *(float4*)&escT[t * 128 + r4] = ev;
        mp[tid] = make_float4(x, y, zz, -0.5f * (x * x + y * y + zz * zz));
    }
    __builtin_amdgcn_sched_barrier(0);
    #pragma unroll
    for (int i = 0; i < 4; ++i) {         // stage buf0 (K-step 0): 4 gld_lds
        const int seg = wave * 4 + i;
        const int tt = seg >> 1, oh = (seg & 1) * 16;
        gld_lds16((char*)Bs[0] + seg * 1024 + lane * 16,
                  gB + (size_t)(tt * 64 + oh + r16) * 1024 + gsw * 8);
    }
    asm volatile("s_waitcnt lgkmcnt(0)" ::: "memory");  // publish escT/mp only
    __builtin_amdgcn_s_barrier();

    f32x4_t acc[2][16];
    #pragma unroll
    for (int i = 0; i < 2; ++i)
        #pragma unroll
        for (int j = 0; j < 16; ++j) acc[i][j] = f32x4_t{0.f, 0.f, 0.f, 0.f};

    for (int kk = 0; kk < 8; ++kk) {
        const int cur = kk & 1;
        if (kk < 7) {                     // stage next K-step into other buffer
            const int k0n = (kk + 1) * 32;
            #pragma unroll
            for (int i = 0; i < 4; ++i) {
                const int seg = wave * 4 + i;
                const int tt = seg >> 1, oh = (seg & 1) * 16;
                gld_lds16((char*)Bs[cur ^ 1] + seg * 1024 + lane * 16,
                          gB + (size_t)(tt * 64 + oh + r16) * 1024 + k0n + gsw * 8);
            }
        }
        // compute A fragments in registers — overlaps both buffers' DMA
        uint4 afr0, afr1;
        {
            unsigned short u0[8], u1[8];
            const int mbase = kk * 32 + quad * 8;
            #pragma unroll
            for (int j = 0; j < 8; ++j) {
                const float4 m4 = mp[mbase + j];
                const float e0 = __expf(rh0 + m4.w + rx0 * m4.x + ry0 * m4.y + rz0 * m4.z);
                const float e1 = __expf(rh1 + m4.w + rx1 * m4.x + ry1 * m4.y + rz1 * m4.z);
                u0[j] = f2bf(e0);
                u1[j] = f2bf(e1);
            }
            afr0.x = u0[0] | ((unsigned)u0[1] << 16);
            afr0.y = u0[2] | ((unsigned)u0[3] << 16);
            afr0.z = u0[4] | ((unsigned)u0[5] << 16);
            afr0.w = u0[6] | ((unsigned)u0[7] << 16);
            afr1.x = u1[0] | ((unsigned)u1[1] << 16);
            afr1.y = u1[2] | ((unsigned)u1[3] << 16);
            afr1.z = u1[4] | ((unsigned)u1[5] << 16);
            afr1.w = u1[6] | ((unsigned)u1[7] << 16);
        }
        // counted drain: wait only the CURRENT buffer's 4 DMAs (oldest);
        // the 4 next-buffer DMAs stay in flight across the barrier.
        if (kk < 7) asm volatile("s_waitcnt vmcnt(4)" ::: "memory");
        else        asm volatile("s_waitcnt vmcnt(0)" ::: "memory");
        __builtin_amdgcn_s_barrier();
        __builtin_amdgcn_sched_barrier(0);
        #pragma unroll
        for (int j = 0; j < 16; ++j) {    // one B-frag live at a time
            uint4 bfr = *(const uint4*)((const char*)Bs[cur] + (j * 16 + fr) * 64 + swoff);
            acc[0][j] = __builtin_amdgcn_mfma_f32_16x16x32_bf16(
                __builtin_bit_cast(bf16x8_t, afr0),
                __builtin_bit_cast(bf16x8_t, bfr), acc[0][j], 0, 0, 0);
            acc[1][j] = __builtin_amdgcn_mfma_f32_16x16x32_bf16(
                __builtin_bit_cast(bf16x8_t, afr1),
                __builtin_bit_cast(bf16x8_t, bfr), acc[1][j], 0, 0, 0);
        }
        if (kk < 7) __builtin_amdgcn_s_barrier();  // protect buf[cur] before
    }                                              // next iter's DMA reuses it

    // epilogue: res[row][o] = sum_t escT[t][row] * acc — all in registers.
    // frag j covers t = j>>1, channel = ogp*32 + (j&1)*16 + fr.
    const int oo = lane & 15;
    unsigned short* dst = He2 + (size_t)kh * 524288
                              + (size_t)(b * 1024 + n0) * 64 + ogp * 32;
    #pragma unroll
    for (int i = 0; i < 2; ++i) {
        #pragma unroll
        for (int r = 0; r < 4; ++r) {
            const int row = row_base + i * 16 + quad * 4 + r;
            float s0 = 0.f, s1 = 0.f;
            #pragma unroll
            for (int t = 0; t < 8; ++t) {
                const float e = escT[t * 128 + row];
                s0 += e * acc[i][2 * t][r];
                s1 += e * acc[i][2 * t + 1][r];
            }
            dst[(size_t)row * 64 + oo] = f2bf(s0);
            dst[(size_t)row * 64 + 16 + oo] = f2bf(s1);
        }
    }
}

// K4: out = sum of 4 bf16 He2 partials; fused BN sum/sumsq.
// XCD-matched remap: data-b == blockIdx&7 == XCD (same swizzle as producers).
__global__ __launch_bounds__(256) void k_fin(const unsigned short* __restrict__ He2,
                                             float* __restrict__ out,
                                             float* __restrict__ bns) {
    __shared__ float s1[16][64], s2[16][64];
    const int tid = threadIdx.x;
    const int vb = ((blockIdx.x & 7) << 5) | (blockIdx.x >> 3);  // bijective
    float a0 = 0.f, a1 = 0.f, a2 = 0.f, a3 = 0.f;
    float q0 = 0.f, q1 = 0.f, q2 = 0.f, q3 = 0.f;
    #pragma unroll
    for (int it = 0; it < 2; ++it) {
        const size_t idx = (size_t)vb * 512 + it * 256 + tid;    // ushort4 group
        float4 s = make_float4(0.f, 0.f, 0.f, 0.f);
        #pragma unroll
        for (int p = 0; p < 4; ++p) {
            ushort4 u = *(const ushort4*)(He2 + (size_t)p * 524288 + idx * 4);
            s.x += bf2f(u.x); s.y += bf2f(u.y); s.z += bf2f(u.z); s.w += bf2f(u.w);
        }
        ((float4*)out)[idx] = s;
        a0 += s.x; a1 += s.y; a2 += s.z; a3 += s.w;
        q0 += s.x * s.x; q1 += s.y * s.y; q2 += s.z * s.z; q3 += s.w * s.w;
    }
    const int g = tid >> 4, o4 = (tid & 15) * 4;
    *(float4*)&s1[g][o4] = make_float4(a0, a1, a2, a3);
    *(float4*)&s2[g][o4] = make_float4(q0, q1, q2, q3);
    __syncthreads();
    if (tid < 64) {
        float sa = 0.f, sb = 0.f;
        #pragma unroll
        for (int r = 0; r < 16; ++r) { sa += s1[r][tid]; sb += s2[r][tid]; }
        atomicAdd(&bns[tid], sa);
        atomicAdd(&bns[64 + tid], sb);
    }
}

// K5: in-place BN (training stats) + ReLU. XCD-matched remap like k_fin.
__global__ __launch_bounds__(256) void k_bn(float* __restrict__ out,
                                            const float* __restrict__ bns,
                                            const float* __restrict__ gamma,
                                            const float* __restrict__ beta) {
    const int vb = ((blockIdx.x & 7) << 6) | (blockIdx.x >> 3);  // bijective
    const int i = vb * 256 + threadIdx.x;
    const int o4 = (i & 15) * 4;
    float4 x = ((float4*)out)[i];
    const float4 s  = *(const float4*)&bns[o4];
    const float4 s2 = *(const float4*)&bns[64 + o4];
    const float4 gm = *(const float4*)&gamma[o4];
    const float4 bt = *(const float4*)&beta[o4];
    const float invn = 1.f / 8192.f;
    float m, v, w;
    m = s.x * invn; v = s2.x * invn - m * m; w = __frsqrt_rn(v + BN_EPS) * gm.x;
    x.x = fmaxf((x.x - m) * w + bt.x, 0.f);
    m = s.y * invn; v = s2.y * invn - m * m; w = __frsqrt_rn(v + BN_EPS) * gm.y;
    x.y = fmaxf((x.y - m) * w + bt.y, 0.f);
    m = s.z * invn; v = s2.z * invn - m * m; w = __frsqrt_rn(v + BN_EPS) * gm.z;
    x.z = fmaxf((x.z - m) * w + bt.z, 0.f);
    m = s.w * invn; v = s2.w * invn - m * m; w = __frsqrt_rn(v + BN_EPS) * gm.w;
    x.w = fmaxf((x.w - m) * w + bt.w, 0.f);
    ((float4*)out)[i] = x;
}

extern "C" void kernel_launch(void* const* d_in, const int* in_sizes, int n_in,
                              void* d_out, int out_size, void* d_ws, size_t ws_size,
                              hipStream_t stream) {
    const float* points = (const float*)d_in[0];
    const float* trans  = (const float*)d_in[1];
    const float* funcs  = (const float*)d_in[2];
    const float* ktens  = (const float*)d_in[3];
    const float* gamma  = (const float*)d_in[4];
    const float* beta   = (const float*)d_in[5];
    float* out = (float*)d_out;

    float* ws      = (float*)d_ws;
    float* escale  = ws;                    // 65536 f
    float* bns     = escale + 65536;        // 128 f
    float* rowsum  = bns + 128;             // 8192 f
    unsigned short* He2   = (unsigned short*)(rowsum + 8192);   // 2097152 us (4 MB)
    unsigned short* kpb   = He2 + 2097152;                      // 32768 us
    unsigned short* bmatT = kpb + 32768;                        // 4194304 us (8 MB)

    k_g<<<640, 256, 0, stream>>>(points, ktens, rowsum, kpb, bns);
    k_prep<<<256, 256, 0, stream>>>(points, trans, funcs, kpb, rowsum, bmatT, escale);
    k_gemm<<<512, 256, 0, stream>>>(points, bmatT, escale, He2);
    k_fin<<<256, 256, 0, stream>>>(He2, out, bns);
    k_bn<<<512, 256, 0, stream>>>(out, bns, gamma, beta);
}

// Round 4
// 103.094 us; speedup vs baseline: 1.0397x; 1.0397x over previous
//
#include <hip/hip_runtime.h>
#include <hip/hip_bf16.h>
#include <cstdint>
#include <cstddef>

#define BN_EPS 1e-5f

typedef float f32x4_t __attribute__((ext_vector_type(4)));
typedef __bf16 bf16x8_t __attribute__((ext_vector_type(8)));

__device__ __forceinline__ unsigned short f2bf(float f) {
    __hip_bfloat16 h = __float2bfloat16(f);
    return __builtin_bit_cast(unsigned short, h);
}
__device__ __forceinline__ float bf2f(unsigned short u) {
    unsigned int v = ((unsigned int)u) << 16;
    return __builtin_bit_cast(float, v);
}

// async global->LDS, 16B/lane; LDS dest is wave-uniform base + lane*16.
__device__ __forceinline__ void gld_lds16(void* lds, const void* gp) {
#if __has_builtin(__builtin_amdgcn_global_load_lds)
    __builtin_amdgcn_global_load_lds(
        (const __attribute__((address_space(1))) unsigned int*)gp,
        (__attribute__((address_space(3))) unsigned int*)lds, 16, 0, 0);
#else
    *(uint4*)lds = *(const uint4*)gp;
#endif
}

// ---------------- ws layout ----------------
// escale : float [B][T][N]                65536 f
// bns    : float sum[64]+sumsq[64]        128 f
// rowsum : float [B][N]                   8192 f
// He2    : bf16  [4 part][B*N][64]        2097152 us (4 MB)
// bmatT  : bf16  [B][512 col][N(m)]       4194304 us (8 MB)
//
// R0: G (16 MB) eliminated; k_gemm recomputes the Gaussian A-operand in regs.
// R1: og 4->2 merge in k_gemm (acc[2][16], grid 512, 2 blk/CU). -6.3 us.
// R2: dbuf+counted-vmcnt k_gemm was +1 us (m141-style: extra barrier + pinned
//     schedule defeats compiler; wave overlap already hid the drain). REVERTED.
//     Kept: XCD-matched k_fin/k_bn remap, 16-row k_g.
// R3 (this round): fold 1/rowsum out of bmatT into k_gemm's A-exponent
//     (mp.w += -ln rowsum[m]; algebraically identical product). k_prep then
//     depends on NOTHING from k_g (stages its k-slice straight from ktens),
//     so k_g+k_prep fuse into ONE launch (disjoint block ranges, LDS union).
//     5 launches -> 4; kpb round-trip eliminated.
// NOTE (prior-session lesson): device-scope ticket-barrier fusion cost ~20 us;
// keep k_fin/k_bn as separate launches. BK=64 crosses VGPR cliff; keep BK=32.

union SmemGP {
    struct {   // rowsum branch (38.9 KB)
        float praw[3072];
        float px[1024], py[1024], pz[1024], hq[1024];
        float part[16][128];
        float p2[16][32];
    } g;
    struct {   // prep branch (37.9 KB)
        unsigned short Asm[128 * 72];
        unsigned short Bsm[128 * 72];
        float sfacl[256];
    } p;
};

// K1 (fused): blocks 0..511: rowsum, 16 rows/block, XCD swizzle b=bk&7.
//             blocks 512..767: prep GEMM (independent of rowsum branch).
__global__ __launch_bounds__(256) void k_gp(const float* __restrict__ points,
                                            const float* __restrict__ trans,
                                            const float* __restrict__ funcs,
                                            const float* __restrict__ ktens,
                                            float* __restrict__ rowsum,
                                            unsigned short* __restrict__ bmatT,
                                            float* __restrict__ escale,
                                            float* __restrict__ bns) {
    __shared__ SmemGP smu;
    const int tid = threadIdx.x;

    if (blockIdx.x >= 512) {
        // ================= prep branch =================
        // bmat[m][col] = sfac[t,m] * sum_c funcs[m,c]*kt[col,c]   (NO /rowsum)
        // bk: b(8) x mt(8,128 rows) x ct(4, t-pair of 128 cols); 4 waves; K=64.
        const int bk = blockIdx.x - 512;
        const int b  = bk & 7;
        const int mt = (bk >> 3) & 7;
        const int ct = bk >> 6;            // 0..3 (t-pair)
        const int m0 = mt * 128;

        unsigned short* Asm = smu.p.Asm;   // [m][c] bf16, stride 72
        unsigned short* Bsm = smu.p.Bsm;   // [col][c] bf16, stride 72
        float* sfacl = smu.p.sfacl;        // [tloc(2)][m(128)]

        if (blockIdx.x == 512 && tid < 128) bns[tid] = 0.f;

        const int wave = tid >> 6, lane = tid & 63;
        const int wr = wave >> 1, wc = wave & 1;
        const int fr = lane & 15, quad = lane >> 4;

        // sfac + escale (global reads only; no LDS dependency)
        {
            const int tloc = tid >> 7, m = tid & 127;
            const int t = ct * 2 + tloc;
            const float tx = trans[b * 24 + t * 3], ty = trans[b * 24 + t * 3 + 1],
                        tz = trans[b * 24 + t * 3 + 2];
            const float* pp = &points[(size_t)(b * 1024 + m0 + m) * 3];
            const float ptd = pp[0] * tx + pp[1] * ty + pp[2] * tz;
            const float tsq = tx * tx + ty * ty + tz * tz;
            sfacl[tloc * 128 + m] = __expf(-ptd - 0.5f * tsq);
            escale[(size_t)(b * 8 + t) * 1024 + m0 + m] = __expf(ptd);
        }
        // stage A: funcs fp32 -> bf16 LDS [m][c]
        #pragma unroll
        for (int rep = 0; rep < 2; ++rep) {
            const int m = rep * 64 + (tid >> 2);
            const int c16 = (tid & 3) * 16;
            const float* fp = &funcs[((size_t)(b * 1024) + m0 + m) * 64 + c16];
            float4 f0 = *(const float4*)fp, f1 = *(const float4*)(fp + 4);
            float4 f2 = *(const float4*)(fp + 8), f3 = *(const float4*)(fp + 12);
            uint4 p0, p1;
            p0.x = f2bf(f0.x) | ((unsigned)f2bf(f0.y) << 16);
            p0.y = f2bf(f0.z) | ((unsigned)f2bf(f0.w) << 16);
            p0.z = f2bf(f1.x) | ((unsigned)f2bf(f1.y) << 16);
            p0.w = f2bf(f1.z) | ((unsigned)f2bf(f1.w) << 16);
            p1.x = f2bf(f2.x) | ((unsigned)f2bf(f2.y) << 16);
            p1.y = f2bf(f2.z) | ((unsigned)f2bf(f2.w) << 16);
            p1.z = f2bf(f3.x) | ((unsigned)f2bf(f3.y) << 16);
            p1.w = f2bf(f3.z) | ((unsigned)f2bf(f3.w) << 16);
            *(uint4*)&Asm[m * 72 + c16] = p0;
            *(uint4*)&Asm[m * 72 + c16 + 8] = p1;
        }
        // stage B: directly from ktens (kpb round-trip removed).
        // col g = t*64+o; value[c] = ktens[(o*64+c)*8 + t]
        #pragma unroll
        for (int rep = 0; rep < 4; ++rep) {
            const int col = rep * 32 + (tid >> 3);   // 0..127
            const int c8  = (tid & 7) * 8;
            const int g   = ct * 128 + col;
            const int t   = g >> 6, o = g & 63;
            const float* kt = &ktens[(size_t)(o * 64 + c8) * 8 + t];
            unsigned short us[8];
            #pragma unroll
            for (int q = 0; q < 8; ++q) us[q] = f2bf(kt[q * 8]);
            uint4 v;
            v.x = us[0] | ((unsigned)us[1] << 16);
            v.y = us[2] | ((unsigned)us[3] << 16);
            v.z = us[4] | ((unsigned)us[5] << 16);
            v.w = us[6] | ((unsigned)us[7] << 16);
            *(uint4*)&Bsm[col * 72 + c8] = v;
        }
        __syncthreads();

        f32x4_t acc[4][4];
        #pragma unroll
        for (int i = 0; i < 4; ++i)
            #pragma unroll
            for (int j = 0; j < 4; ++j) acc[i][j] = f32x4_t{0.f, 0.f, 0.f, 0.f};

        #pragma unroll
        for (int s = 0; s < 2; ++s) {
            uint4 afr[4], bfr[4];
            #pragma unroll
            for (int i = 0; i < 4; ++i)
                afr[i] = *(const uint4*)&Asm[(wr * 64 + i * 16 + fr) * 72 + s * 32 + quad * 8];
            #pragma unroll
            for (int j = 0; j < 4; ++j)
                bfr[j] = *(const uint4*)&Bsm[(wc * 64 + j * 16 + fr) * 72 + s * 32 + quad * 8];
            #pragma unroll
            for (int i = 0; i < 4; ++i)
                #pragma unroll
                for (int j = 0; j < 4; ++j)
                    acc[i][j] = __builtin_amdgcn_mfma_f32_16x16x32_bf16(
                        __builtin_bit_cast(bf16x8_t, afr[i]),
                        __builtin_bit_cast(bf16x8_t, bfr[j]),
                        acc[i][j], 0, 0, 0);
        }

        // epilogue: scale and pack 4 consecutive m per lane -> bmatT[b][col][m]
        #pragma unroll
        for (int i = 0; i < 4; ++i) {
            #pragma unroll
            for (int j = 0; j < 4; ++j) {
                const int colg = ct * 128 + wc * 64 + j * 16 + fr;
                ushort4 pk;
                const int mb = wr * 64 + i * 16 + quad * 4;
                pk.x = f2bf(acc[i][j][0] * sfacl[wc * 128 + mb + 0]);
                pk.y = f2bf(acc[i][j][1] * sfacl[wc * 128 + mb + 1]);
                pk.z = f2bf(acc[i][j][2] * sfacl[wc * 128 + mb + 2]);
                pk.w = f2bf(acc[i][j][3] * sfacl[wc * 128 + mb + 3]);
                *(ushort4*)&bmatT[(size_t)(b * 512 + colg) * 1024 + m0 + mb] = pk;
            }
        }
        return;
    }

    // ================= rowsum branch =================
    float* praw = smu.g.praw;
    float* px = smu.g.px; float* py = smu.g.py;
    float* pz = smu.g.pz; float* hq = smu.g.hq;
    float (*part)[128] = smu.g.part;
    float (*p2)[32] = smu.g.p2;

    const int b  = blockIdx.x & 7;               // XCD swizzle
    const int n0 = (blockIdx.x >> 3) * 16;

    for (int i = tid; i < 3072; i += 256) praw[i] = points[b * 3072 + i];
    __syncthreads();
    for (int n = tid; n < 1024; n += 256) {
        float x = praw[n * 3], y = praw[n * 3 + 1], z = praw[n * 3 + 2];
        px[n] = x; py[n] = y; pz[n] = z;
        hq[n] = -0.5f * (x * x + y * y + z * z);
    }
    __syncthreads();

    const int rhalf = tid >> 7;                  // 0/1: which row of the pair
    const int c0 = (tid & 127) * 8;              // column octet
    float vx[8], vy[8], vz[8], vh[8];
    *(float4*)&vx[0] = *(const float4*)&px[c0];
    *(float4*)&vx[4] = *(const float4*)&px[c0 + 4];
    *(float4*)&vy[0] = *(const float4*)&py[c0];
    *(float4*)&vy[4] = *(const float4*)&py[c0 + 4];
    *(float4*)&vz[0] = *(const float4*)&pz[c0];
    *(float4*)&vz[4] = *(const float4*)&pz[c0 + 4];
    *(float4*)&vh[0] = *(const float4*)&hq[c0];
    *(float4*)&vh[4] = *(const float4*)&hq[c0 + 4];

    #pragma unroll
    for (int u = 0; u < 8; ++u) {
        const int rl = u * 2 + rhalf;            // 0..15
        const int row = n0 + rl;
        const float rx = px[row], ry = py[row], rz = pz[row], hr = hq[row];
        float ssum = 0.f;
        #pragma unroll
        for (int j = 0; j < 8; ++j)
            ssum += __expf(hr + vh[j] + rx * vx[j] + ry * vy[j] + rz * vz[j]);
        part[rl][tid & 127] = ssum;
    }
    __syncthreads();
    #pragma unroll
    for (int rep = 0; rep < 2; ++rep) {   // level 1: 128 -> 32 partials per row
        const int row = rep * 8 + (tid >> 5), c4l = (tid & 31) * 4;
        float4 p = *(const float4*)&part[row][c4l];
        p2[row][tid & 31] = p.x + p.y + p.z + p.w;
    }
    __syncthreads();
    if (tid < 16) {   // level 2: 16 thr finish their row
        float s = 0.f;
        #pragma unroll
        for (int q = 0; q < 8; ++q) {
            float4 v = *(const float4*)&p2[tid][q * 4];
            s += v.x + v.y + v.z + v.w;
        }
        rowsum[b * 1024 + n0 + tid] = s;
    }
}

// K3: FUSED Gaussian + bf16 GEMM, BK=32, og-pair merged (R1 structure,
// measured 106.2; R2's dbuf reverted). 1/rowsum[m] folded into the exponent:
// A[r][m] = exp(hr + (hm - ln rowsum[m]) + p.r)  — mp.w carries the fold.
// grid 512 = b(8) x rt(8) x [ogp(2) x kh(4)]; 4 waves; 128 rows x 256 cols.
__global__ __launch_bounds__(256, 2) void k_gemm(const float* __restrict__ points,
                                                 const unsigned short* __restrict__ bmatT,
                                                 const float* __restrict__ escale,
                                                 const float* __restrict__ rowsum,
                                                 unsigned short* __restrict__ He2) {
    __shared__ unsigned short Bs[8192];   // [c'(256)=t*32+oo][k(32)] bf16, k-swizzled
    __shared__ float escT[1024];          // [t(8)][row(128)]
    __shared__ float4 mp[256];            // m-points: x,y,z, hq - ln(rowsum)

    const int b  = blockIdx.x & 7;        // XCD swizzle
    const int rt = (blockIdx.x >> 3) & 7;
    const int z  = blockIdx.x >> 6;       // 0..7
    const int ogp = z & 1;                // channel half (32 ch)
    const int kh  = z >> 1;               // K quarter
    const int n0 = rt * 128;
    const int kb = kh * 256;

    const int tid  = threadIdx.x;
    const int wave = tid >> 6, lane = tid & 63;

    {   // stage escale [8t][128 rows]
        const int t = tid >> 5, r4 = (tid & 31) * 4;
        *(float4*)&escT[t * 128 + r4] =
            *(const float4*)&escale[(size_t)(b * 8 + t) * 1024 + n0 + r4];
    }
    {   // stage the 256 m-points: (x,y,z, hq - ln rowsum)  [rowsum fold]
        const float* pp = &points[(size_t)(b * 1024 + kb + tid) * 3];
        const float x = pp[0], y = pp[1], zz = pp[2];
        const float rs = rowsum[b * 1024 + kb + tid];
        mp[tid] = make_float4(x, y, zz,
                              -0.5f * (x * x + y * y + zz * zz) - __logf(rs));
    }

    const unsigned short* gB = bmatT + (size_t)(b * 512 + ogp * 32) * 1024 + kb;

    const int r16 = lane >> 2;            // row within 16-seg
    const int kq  = lane & 3;             // dest 16B k-group
    const int gsw = kq ^ (r16 & 3);       // swizzled source k-group

    const int fr = lane & 15;             // fragment row part
    const int quad = lane >> 4;           // fragment k part
    const int swoff = (quad ^ (fr & 3)) << 4;   // swizzled frag byte offset
    const int row_base = wave * 32;       // this wave's 32 output rows

    // row registers: this lane's 2 fixed A-rows
    float rx0, ry0, rz0, rh0, rx1, ry1, rz1, rh1;
    {
        const float* p0 = &points[(size_t)(b * 1024 + n0 + row_base + fr) * 3];
        rx0 = p0[0]; ry0 = p0[1]; rz0 = p0[2];
        rh0 = -0.5f * (rx0 * rx0 + ry0 * ry0 + rz0 * rz0);
        const float* p1 = &points[(size_t)(b * 1024 + n0 + row_base + 16 + fr) * 3];
        rx1 = p1[0]; ry1 = p1[1]; rz1 = p1[2];
        rh1 = -0.5f * (rx1 * rx1 + ry1 * ry1 + rz1 * rz1);
    }

    f32x4_t acc[2][16];
    #pragma unroll
    for (int i = 0; i < 2; ++i)
        #pragma unroll
        for (int j = 0; j < 16; ++j) acc[i][j] = f32x4_t{0.f, 0.f, 0.f, 0.f};

    for (int kk = 0; kk < 8; ++kk) {
        const int k0 = kk * 32;
        __syncthreads();                  // prev Bs consumed (kk=0: mp/escT ready)
        #pragma unroll
        for (int i = 0; i < 4; ++i) {     // stage Bs: 16 segs of 16 c' (4/thread)
            const int seg = wave * 4 + i; // c' = seg*16 + r16 -> t = seg>>1, oo
            const int t = seg >> 1, oh = (seg & 1) * 16;
            gld_lds16((char*)Bs + seg * 1024 + lane * 16,
                      gB + (size_t)(t * 64 + oh + r16) * 1024 + k0 + gsw * 8);
        }
        // compute A fragments in registers — overlaps Bs load latency
        uint4 afr0, afr1;
        {
            unsigned short u0[8], u1[8];
            const int mbase = k0 + quad * 8;
            #pragma unroll
            for (int j = 0; j < 8; ++j) {
                const float4 m4 = mp[mbase + j];
                const float e0 = __expf(rh0 + m4.w + rx0 * m4.x + ry0 * m4.y + rz0 * m4.z);
                const float e1 = __expf(rh1 + m4.w + rx1 * m4.x + ry1 * m4.y + rz1 * m4.z);
                u0[j] = f2bf(e0);
                u1[j] = f2bf(e1);
            }
            afr0.x = u0[0] | ((unsigned)u0[1] << 16);
            afr0.y = u0[2] | ((unsigned)u0[3] << 16);
            afr0.z = u0[4] | ((unsigned)u0[5] << 16);
            afr0.w = u0[6] | ((unsigned)u0[7] << 16);
            afr1.x = u1[0] | ((unsigned)u1[1] << 16);
            afr1.y = u1[2] | ((unsigned)u1[3] << 16);
            afr1.z = u1[4] | ((unsigned)u1[5] << 16);
            afr1.w = u1[6] | ((unsigned)u1[7] << 16);
        }
        __syncthreads();                  // DMA drained -> Bs visible
        #pragma unroll
        for (int j = 0; j < 16; ++j) {    // one B-frag live at a time
            uint4 bfr = *(const uint4*)((const char*)Bs + (j * 16 + fr) * 64 + swoff);
            acc[0][j] = __builtin_amdgcn_mfma_f32_16x16x32_bf16(
                __builtin_bit_cast(bf16x8_t, afr0),
                __builtin_bit_cast(bf16x8_t, bfr), acc[0][j], 0, 0, 0);
            acc[1][j] = __builtin_amdgcn_mfma_f32_16x16x32_bf16(
                __builtin_bit_cast(bf16x8_t, afr1),
                __builtin_bit_cast(bf16x8_t, bfr), acc[1][j], 0, 0, 0);
        }
    }

    // epilogue: res[row][o] = sum_t escT[t][row] * acc — all in registers.
    // frag j covers t = j>>1, channel = ogp*32 + (j&1)*16 + fr.
    const int oo = lane & 15;
    unsigned short* dst = He2 + (size_t)kh * 524288
                              + (size_t)(b * 1024 + n0) * 64 + ogp * 32;
    #pragma unroll
    for (int i = 0; i < 2; ++i) {
        #pragma unroll
        for (int r = 0; r < 4; ++r) {
            const int row = row_base + i * 16 + quad * 4 + r;
            float s0 = 0.f, s1 = 0.f;
            #pragma unroll
            for (int t = 0; t < 8; ++t) {
                const float e = escT[t * 128 + row];
                s0 += e * acc[i][2 * t][r];
                s1 += e * acc[i][2 * t + 1][r];
            }
            dst[(size_t)row * 64 + oo] = f2bf(s0);
            dst[(size_t)row * 64 + 16 + oo] = f2bf(s1);
        }
    }
}

// K4: out = sum of 4 bf16 He2 partials; fused BN sum/sumsq.
// XCD-matched remap: data-b == blockIdx&7 == XCD (same swizzle as producers).
__global__ __launch_bounds__(256) void k_fin(const unsigned short* __restrict__ He2,
                                             float* __restrict__ out,
                                             float* __restrict__ bns) {
    __shared__ float s1[16][64], s2[16][64];
    const int tid = threadIdx.x;
    const int vb = ((blockIdx.x & 7) << 5) | (blockIdx.x >> 3);  // bijective
    float a0 = 0.f, a1 = 0.f, a2 = 0.f, a3 = 0.f;
    float q0 = 0.f, q1 = 0.f, q2 = 0.f, q3 = 0.f;
    #pragma unroll
    for (int it = 0; it < 2; ++it) {
        const size_t idx = (size_t)vb * 512 + it * 256 + tid;    // ushort4 group
        float4 s = make_float4(0.f, 0.f, 0.f, 0.f);
        #pragma unroll
        for (int p = 0; p < 4; ++p) {
            ushort4 u = *(const ushort4*)(He2 + (size_t)p * 524288 + idx * 4);
            s.x += bf2f(u.x); s.y += bf2f(u.y); s.z += bf2f(u.z); s.w += bf2f(u.w);
        }
        ((float4*)out)[idx] = s;
        a0 += s.x; a1 += s.y; a2 += s.z; a3 += s.w;
        q0 += s.x * s.x; q1 += s.y * s.y; q2 += s.z * s.z; q3 += s.w * s.w;
    }
    const int g = tid >> 4, o4 = (tid & 15) * 4;
    *(float4*)&s1[g][o4] = make_float4(a0, a1, a2, a3);
    *(float4*)&s2[g][o4] = make_float4(q0, q1, q2, q3);
    __syncthreads();
    if (tid < 64) {
        float sa = 0.f, sb = 0.f;
        #pragma unroll
        for (int r = 0; r < 16; ++r) { sa += s1[r][tid]; sb += s2[r][tid]; }
        atomicAdd(&bns[tid], sa);
        atomicAdd(&bns[64 + tid], sb);
    }
}

// K5: in-place BN (training stats) + ReLU. XCD-matched remap like k_fin.
__global__ __launch_bounds__(256) void k_bn(float* __restrict__ out,
                                            const float* __restrict__ bns,
                                            const float* __restrict__ gamma,
                                            const float* __restrict__ beta) {
    const int vb = ((blockIdx.x & 7) << 6) | (blockIdx.x >> 3);  // bijective
    const int i = vb * 256 + threadIdx.x;
    const int o4 = (i & 15) * 4;
    float4 x = ((float4*)out)[i];
    const float4 s  = *(const float4*)&bns[o4];
    const float4 s2 = *(const float4*)&bns[64 + o4];
    const float4 gm = *(const float4*)&gamma[o4];
    const float4 bt = *(const float4*)&beta[o4];
    const float invn = 1.f / 8192.f;
    float m, v, w;
    m = s.x * invn; v = s2.x * invn - m * m; w = __frsqrt_rn(v + BN_EPS) * gm.x;
    x.x = fmaxf((x.x - m) * w + bt.x, 0.f);
    m = s.y * invn; v = s2.y * invn - m * m; w = __frsqrt_rn(v + BN_EPS) * gm.y;
    x.y = fmaxf((x.y - m) * w + bt.y, 0.f);
    m = s.z * invn; v = s2.z * invn - m * m; w = __frsqrt_rn(v + BN_EPS) * gm.z;
    x.z = fmaxf((x.z - m) * w + bt.z, 0.f);
    m = s.w * invn; v = s2.w * invn - m * m; w = __frsqrt_rn(v + BN_EPS) * gm.w;
    x.w = fmaxf((x.w - m) * w + bt.w, 0.f);
    ((float4*)out)[i] = x;
}

extern "C" void kernel_launch(void* const* d_in, const int* in_sizes, int n_in,
                              void* d_out, int out_size, void* d_ws, size_t ws_size,
                              hipStream_t stream) {
    const float* points = (const float*)d_in[0];
    const float* trans  = (const float*)d_in[1];
    const float* funcs  = (const float*)d_in[2];
    const float* ktens  = (const float*)d_in[3];
    const float* gamma  = (const float*)d_in[4];
    const float* beta   = (const float*)d_in[5];
    float* out = (float*)d_out;

    float* ws      = (float*)d_ws;
    float* escale  = ws;                    // 65536 f
    float* bns     = escale + 65536;        // 128 f
    float* rowsum  = bns + 128;             // 8192 f
    unsigned short* He2   = (unsigned short*)(rowsum + 8192);   // 2097152 us (4 MB)
    unsigned short* bmatT = He2 + 2097152;                      // 4194304 us (8 MB)

    k_gp<<<768, 256, 0, stream>>>(points, trans, funcs, ktens,
                                  rowsum, bmatT, escale, bns);
    k_gemm<<<512, 256, 0, stream>>>(points, bmatT, escale, rowsum, He2);
    k_fin<<<256, 256, 0, stream>>>(He2, out, bns);
    k_bn<<<512, 256, 0, stream>>>(out, bns, gamma, beta);
}

// Round 6
// 102.364 us; speedup vs baseline: 1.0471x; 1.0071x over previous
//
#include <hip/hip_runtime.h>
#include <hip/hip_bf16.h>
#include <cstdint>
#include <cstddef>
#include <cstring>

#define BN_EPS 1e-5f
#define L2E 1.4426950408889634f

typedef float f32x4_t __attribute__((ext_vector_type(4)));
typedef __bf16 bf16x8_t __attribute__((ext_vector_type(8)));

__device__ __forceinline__ unsigned short f2bf(float f) {
    __hip_bfloat16 h = __float2bfloat16(f);
    return __builtin_bit_cast(unsigned short, h);
}
__device__ __forceinline__ float bf2f(unsigned short u) {
    unsigned int v = ((unsigned int)u) << 16;
    return __builtin_bit_cast(float, v);
}
// packed bf16 pair: a -> low16, b -> high16 (memcpy: __hip_bfloat162 is not
// trivially copyable for __builtin_bit_cast; memcpy lowers to a reg move)
__device__ __forceinline__ unsigned int pkbf(float a, float b) {
    __hip_bfloat162 h = __float22bfloat162_rn(make_float2(a, b));
    unsigned int r;
    __builtin_memcpy(&r, &h, 4);
    return r;
}

// async global->LDS, 16B/lane; LDS dest is wave-uniform base + lane*16.
__device__ __forceinline__ void gld_lds16(void* lds, const void* gp) {
#if __has_builtin(__builtin_amdgcn_global_load_lds)
    __builtin_amdgcn_global_load_lds(
        (const __attribute__((address_space(1))) unsigned int*)gp,
        (__attribute__((address_space(3))) unsigned int*)lds, 16, 0, 0);
#else
    *(uint4*)lds = *(const uint4*)gp;
#endif
}

// ---------------- ws layout ----------------
// escale : float [B][T][N]                65536 f
// bns    : float sum[64]+sumsq[64]        128 f
// rowsum : float [B][N]                   8192 f
// He2    : bf16  [4 part][B*N][64]        2097152 us (4 MB)
// bmatT  : bf16  [B][512 col][N(m)]       4194304 us (8 MB)
//
// R0: G (16 MB) eliminated; A-operand exp recomputed in regs in k_gemm.
// R1: og 4->2 merge (acc[2][16], grid 512, 2 blk/CU). -6.3 us.
// R2: 2-deep dbuf + 3 barriers/K-step regressed (+1 us). Lesson: the extra
//     trailing barrier (W-after-R hazard on 2-deep) ate the gain.
// R3: 1/rowsum folded into A-exponent; k_g+k_prep fused (4 launches). -4.1 us.
// R4/R5 (this round; R4 was a compile break in pkbf, fixed via memcpy):
//  - k_gemm: TRIPLE-buffered Bs -> ONE s_barrier + counted vmcnt(4)/K-step
//    (hazard-free: concurrent W/R buffers always distinct mod 3; W(k+1) stays
//    in flight across the barrier).
//  - log2-domain exp everywhere (fold L2E into row regs/hq; -ln rs = -log2 rs
//    via v_log_f32); packed bf16 stores; float4 escT epilogue reads.
// NOTE: device-scope ticket-barrier fusion cost ~20 us (prior session); keep
// k_fin/k_bn separate. BK=64 crosses VGPR cliff; keep BK=32.

union SmemGP {
    struct {   // rowsum branch (38.9 KB)
        float praw[3072];
        float px[1024], py[1024], pz[1024], hq[1024];
        float part[16][128];
        float p2[16][32];
    } g;
    struct {   // prep branch (37.9 KB)
        unsigned short Asm[128 * 72];
        unsigned short Bsm[128 * 72];
        float sfacl[256];
    } p;
};

// K1 (fused): blocks 0..511: rowsum, 16 rows/block, XCD swizzle b=bk&7.
//             blocks 512..767: prep GEMM (independent of rowsum branch).
__global__ __launch_bounds__(256) void k_gp(const float* __restrict__ points,
                                            const float* __restrict__ trans,
                                            const float* __restrict__ funcs,
                                            const float* __restrict__ ktens,
                                            float* __restrict__ rowsum,
                                            unsigned short* __restrict__ bmatT,
                                            float* __restrict__ escale,
                                            float* __restrict__ bns) {
    __shared__ SmemGP smu;
    const int tid = threadIdx.x;

    if (blockIdx.x >= 512) {
        // ================= prep branch =================
        // bmat[m][col] = sfac[t,m] * sum_c funcs[m,c]*kt[col,c]   (NO /rowsum)
        const int bk = blockIdx.x - 512;
        const int b  = bk & 7;
        const int mt = (bk >> 3) & 7;
        const int ct = bk >> 6;            // 0..3 (t-pair)
        const int m0 = mt * 128;

        unsigned short* Asm = smu.p.Asm;   // [m][c] bf16, stride 72
        unsigned short* Bsm = smu.p.Bsm;   // [col][c] bf16, stride 72
        float* sfacl = smu.p.sfacl;        // [tloc(2)][m(128)]

        if (blockIdx.x == 512 && tid < 128) bns[tid] = 0.f;

        const int wave = tid >> 6, lane = tid & 63;
        const int wr = wave >> 1, wc = wave & 1;
        const int fr = lane & 15, quad = lane >> 4;

        // sfac + escale (global reads only; no LDS dependency)
        {
            const int tloc = tid >> 7, m = tid & 127;
            const int t = ct * 2 + tloc;
            const float tx = trans[b * 24 + t * 3], ty = trans[b * 24 + t * 3 + 1],
                        tz = trans[b * 24 + t * 3 + 2];
            const float* pp = &points[(size_t)(b * 1024 + m0 + m) * 3];
            const float ptd = pp[0] * tx + pp[1] * ty + pp[2] * tz;
            const float tsq = tx * tx + ty * ty + tz * tz;
            sfacl[tloc * 128 + m] = __expf(-ptd - 0.5f * tsq);
            escale[(size_t)(b * 8 + t) * 1024 + m0 + m] = __expf(ptd);
        }
        // stage A: funcs fp32 -> bf16 LDS [m][c]  (packed pairs)
        #pragma unroll
        for (int rep = 0; rep < 2; ++rep) {
            const int m = rep * 64 + (tid >> 2);
            const int c16 = (tid & 3) * 16;
            const float* fp = &funcs[((size_t)(b * 1024) + m0 + m) * 64 + c16];
            float4 f0 = *(const float4*)fp, f1 = *(const float4*)(fp + 4);
            float4 f2 = *(const float4*)(fp + 8), f3 = *(const float4*)(fp + 12);
            uint4 p0, p1;
            p0.x = pkbf(f0.x, f0.y); p0.y = pkbf(f0.z, f0.w);
            p0.z = pkbf(f1.x, f1.y); p0.w = pkbf(f1.z, f1.w);
            p1.x = pkbf(f2.x, f2.y); p1.y = pkbf(f2.z, f2.w);
            p1.z = pkbf(f3.x, f3.y); p1.w = pkbf(f3.z, f3.w);
            *(uint4*)&Asm[m * 72 + c16] = p0;
            *(uint4*)&Asm[m * 72 + c16 + 8] = p1;
        }
        // stage B: directly from ktens. col g = t*64+o; value[c] = ktens[(o*64+c)*8+t]
        #pragma unroll
        for (int rep = 0; rep < 4; ++rep) {
            const int col = rep * 32 + (tid >> 3);   // 0..127
            const int c8  = (tid & 7) * 8;
            const int g   = ct * 128 + col;
            const int t   = g >> 6, o = g & 63;
            const float* kt = &ktens[(size_t)(o * 64 + c8) * 8 + t];
            uint4 v;
            v.x = pkbf(kt[0], kt[8]);
            v.y = pkbf(kt[16], kt[24]);
            v.z = pkbf(kt[32], kt[40]);
            v.w = pkbf(kt[48], kt[56]);
            *(uint4*)&Bsm[col * 72 + c8] = v;
        }
        __syncthreads();

        f32x4_t acc[4][4];
        #pragma unroll
        for (int i = 0; i < 4; ++i)
            #pragma unroll
            for (int j = 0; j < 4; ++j) acc[i][j] = f32x4_t{0.f, 0.f, 0.f, 0.f};

        #pragma unroll
        for (int s = 0; s < 2; ++s) {
            uint4 afr[4], bfr[4];
            #pragma unroll
            for (int i = 0; i < 4; ++i)
                afr[i] = *(const uint4*)&Asm[(wr * 64 + i * 16 + fr) * 72 + s * 32 + quad * 8];
            #pragma unroll
            for (int j = 0; j < 4; ++j)
                bfr[j] = *(const uint4*)&Bsm[(wc * 64 + j * 16 + fr) * 72 + s * 32 + quad * 8];
            #pragma unroll
            for (int i = 0; i < 4; ++i)
                #pragma unroll
                for (int j = 0; j < 4; ++j)
                    acc[i][j] = __builtin_amdgcn_mfma_f32_16x16x32_bf16(
                        __builtin_bit_cast(bf16x8_t, afr[i]),
                        __builtin_bit_cast(bf16x8_t, bfr[j]),
                        acc[i][j], 0, 0, 0);
        }

        // epilogue: scale and pack 4 consecutive m per lane -> bmatT[b][col][m]
        #pragma unroll
        for (int i = 0; i < 4; ++i) {
            #pragma unroll
            for (int j = 0; j < 4; ++j) {
                const int colg = ct * 128 + wc * 64 + j * 16 + fr;
                const int mb = wr * 64 + i * 16 + quad * 4;
                uint2 pk;
                pk.x = pkbf(acc[i][j][0] * sfacl[wc * 128 + mb + 0],
                            acc[i][j][1] * sfacl[wc * 128 + mb + 1]);
                pk.y = pkbf(acc[i][j][2] * sfacl[wc * 128 + mb + 2],
                            acc[i][j][3] * sfacl[wc * 128 + mb + 3]);
                *(uint2*)&bmatT[(size_t)(b * 512 + colg) * 1024 + m0 + mb] = pk;
            }
        }
        return;
    }

    // ================= rowsum branch (log2-domain exp) =================
    float* praw = smu.g.praw;
    float* px = smu.g.px; float* py = smu.g.py;
    float* pz = smu.g.pz; float* hq = smu.g.hq;
    float (*part)[128] = smu.g.part;
    float (*p2)[32] = smu.g.p2;

    const int b  = blockIdx.x & 7;               // XCD swizzle
    const int n0 = (blockIdx.x >> 3) * 16;

    for (int i = tid; i < 3072; i += 256) praw[i] = points[b * 3072 + i];
    __syncthreads();
    for (int n = tid; n < 1024; n += 256) {
        float x = praw[n * 3], y = praw[n * 3 + 1], z = praw[n * 3 + 2];
        px[n] = x; py[n] = y; pz[n] = z;
        hq[n] = -0.5f * L2E * (x * x + y * y + z * z);   // log2-scaled
    }
    __syncthreads();

    const int rhalf = tid >> 7;                  // 0/1: which row of the pair
    const int c0 = (tid & 127) * 8;              // column octet
    float vx[8], vy[8], vz[8], vh[8];
    *(float4*)&vx[0] = *(const float4*)&px[c0];
    *(float4*)&vx[4] = *(const float4*)&px[c0 + 4];
    *(float4*)&vy[0] = *(const float4*)&py[c0];
    *(float4*)&vy[4] = *(const float4*)&py[c0 + 4];
    *(float4*)&vz[0] = *(const float4*)&pz[c0];
    *(float4*)&vz[4] = *(const float4*)&pz[c0 + 4];
    *(float4*)&vh[0] = *(const float4*)&hq[c0];
    *(float4*)&vh[4] = *(const float4*)&hq[c0 + 4];

    #pragma unroll
    for (int u = 0; u < 8; ++u) {
        const int rl = u * 2 + rhalf;            // 0..15
        const int row = n0 + rl;
        // scale ROW side by L2E (col side unscaled; product gets one factor)
        const float rx = L2E * px[row], ry = L2E * py[row], rz = L2E * pz[row];
        const float hr = hq[row];
        float ssum = 0.f;
        #pragma unroll
        for (int j = 0; j < 8; ++j)
            ssum += __builtin_amdgcn_exp2f(hr + vh[j] + rx * vx[j]
                                           + ry * vy[j] + rz * vz[j]);
        part[rl][tid & 127] = ssum;
    }
    __syncthreads();
    #pragma unroll
    for (int rep = 0; rep < 2; ++rep) {   // level 1: 128 -> 32 partials per row
        const int row = rep * 8 + (tid >> 5), c4l = (tid & 31) * 4;
        float4 p = *(const float4*)&part[row][c4l];
        p2[row][tid & 31] = p.x + p.y + p.z + p.w;
    }
    __syncthreads();
    if (tid < 16) {   // level 2: 16 thr finish their row
        float s = 0.f;
        #pragma unroll
        for (int q = 0; q < 8; ++q) {
            float4 v = *(const float4*)&p2[tid][q * 4];
            s += v.x + v.y + v.z + v.w;
        }
        rowsum[b * 1024 + n0 + tid] = s;
    }
}

// K3: FUSED Gaussian + bf16 GEMM, BK=32, og-pair merged, TRIPLE-buffered Bs
// with one s_barrier + counted vmcnt per K-step (R4).
// Hazards: iter k = [W((k+1)%3); A-exp; vmcnt(4); BAR; R(k%3)]. In any barrier
// interval, concurrent W/R buffer indices differ by 2 mod 3 -> disjoint.
// vmcnt: outstanding = W(k)4 + W(k+1)4 = 8 -> vmcnt(4) drains exactly W(k).
// grid 512 = b(8) x rt(8) x [ogp(2) x kh(4)]; 4 waves; 128 rows x 256 cols.
__global__ __launch_bounds__(256, 2) void k_gemm(const float* __restrict__ points,
                                                 const unsigned short* __restrict__ bmatT,
                                                 const float* __restrict__ escale,
                                                 const float* __restrict__ rowsum,
                                                 unsigned short* __restrict__ He2) {
    __shared__ unsigned short Bs[3][8192];  // 3 x [c'(256)=t*32+oo][k(32)], k-swizzled
    __shared__ float escT[1024];            // [t(8)][row(128)]
    __shared__ float4 mp[256];              // m-points: x,y,z, L2E*hq - log2(rowsum)

    const int b  = blockIdx.x & 7;        // XCD swizzle
    const int rt = (blockIdx.x >> 3) & 7;
    const int z  = blockIdx.x >> 6;       // 0..7
    const int ogp = z & 1;                // channel half (32 ch)
    const int kh  = z >> 1;               // K quarter
    const int n0 = rt * 128;
    const int kb = kh * 256;

    const int tid  = threadIdx.x;
    const int wave = tid >> 6, lane = tid & 63;

    const unsigned short* gB = bmatT + (size_t)(b * 512 + ogp * 32) * 1024 + kb;

    const int r16 = lane >> 2;            // row within 16-seg
    const int kq  = lane & 3;             // dest 16B k-group
    const int gsw = kq ^ (r16 & 3);       // swizzled source k-group

    const int fr = lane & 15;             // fragment row part
    const int quad = lane >> 4;           // fragment k part
    const int swoff = (quad ^ (fr & 3)) << 4;   // swizzled frag byte offset
    const int row_base = wave * 32;       // this wave's 32 output rows

    // row registers: this lane's 2 fixed A-rows, log2-scaled
    float rx0, ry0, rz0, rh0, rx1, ry1, rz1, rh1;
    {
        const float* p0 = &points[(size_t)(b * 1024 + n0 + row_base + fr) * 3];
        const float x0 = p0[0], y0 = p0[1], z0 = p0[2];
        rh0 = -0.5f * L2E * (x0 * x0 + y0 * y0 + z0 * z0);
        rx0 = L2E * x0; ry0 = L2E * y0; rz0 = L2E * z0;
        const float* p1 = &points[(size_t)(b * 1024 + n0 + row_base + 16 + fr) * 3];
        const float x1 = p1[0], y1 = p1[1], z1 = p1[2];
        rh1 = -0.5f * L2E * (x1 * x1 + y1 * y1 + z1 * z1);
        rx1 = L2E * x1; ry1 = L2E * y1; rz1 = L2E * z1;
    }
    {   // stage escale [8t][128 rows] + m-points (x,y,z, L2E*hq - log2 rs)
        const int t = tid >> 5, r4 = (tid & 31) * 4;
        float4 ev = *(const float4*)&escale[(size_t)(b * 8 + t) * 1024 + n0 + r4];
        const float* pp = &points[(size_t)(b * 1024 + kb + tid) * 3];
        const float x = pp[0], y = pp[1], zz = pp[2];
        const float rs = rowsum[b * 1024 + kb + tid];
        *(float4*)&escT[t * 128 + r4] = ev;
        mp[tid] = make_float4(x, y, zz,
                              -0.5f * L2E * (x * x + y * y + zz * zz)
                              - __builtin_amdgcn_logf(rs));
    }
    __builtin_amdgcn_sched_barrier(0);
    #pragma unroll
    for (int i = 0; i < 4; ++i) {         // W(0) into Bs[0]
        const int seg = wave * 4 + i;
        const int tt = seg >> 1, oh = (seg & 1) * 16;
        gld_lds16((char*)Bs[0] + seg * 1024 + lane * 16,
                  gB + (size_t)(tt * 64 + oh + r16) * 1024 + gsw * 8);
    }
    asm volatile("s_waitcnt lgkmcnt(0)" ::: "memory");  // publish escT/mp only
    __builtin_amdgcn_s_barrier();

    f32x4_t acc[2][16];
    #pragma unroll
    for (int i = 0; i < 2; ++i)
        #pragma unroll
        for (int j = 0; j < 16; ++j) acc[i][j] = f32x4_t{0.f, 0.f, 0.f, 0.f};

    #pragma unroll
    for (int kk = 0; kk < 8; ++kk) {
        const int cur = kk % 3;
        if (kk < 7) {                     // W(k+1) into Bs[(k+1)%3]
            const int nxt = (kk + 1) % 3;
            const int k0n = (kk + 1) * 32;
            #pragma unroll
            for (int i = 0; i < 4; ++i) {
                const int seg = wave * 4 + i;
                const int tt = seg >> 1, oh = (seg & 1) * 16;
                gld_lds16((char*)Bs[nxt] + seg * 1024 + lane * 16,
                          gB + (size_t)(tt * 64 + oh + r16) * 1024 + k0n + gsw * 8);
            }
        }
        // A fragments in registers (log2 domain, packed bf16)
        uint4 afr0, afr1;
        {
            const int mbase = kk * 32 + quad * 8;
            float e0[8], e1[8];
            #pragma unroll
            for (int j = 0; j < 8; ++j) {
                const float4 m4 = mp[mbase + j];
                e0[j] = __builtin_amdgcn_exp2f(rh0 + m4.w + rx0 * m4.x
                                               + ry0 * m4.y + rz0 * m4.z);
                e1[j] = __builtin_amdgcn_exp2f(rh1 + m4.w + rx1 * m4.x
                                               + ry1 * m4.y + rz1 * m4.z);
            }
            afr0.x = pkbf(e0[0], e0[1]); afr0.y = pkbf(e0[2], e0[3]);
            afr0.z = pkbf(e0[4], e0[5]); afr0.w = pkbf(e0[6], e0[7]);
            afr1.x = pkbf(e1[0], e1[1]); afr1.y = pkbf(e1[2], e1[3]);
            afr1.z = pkbf(e1[4], e1[5]); afr1.w = pkbf(e1[6], e1[7]);
        }
        // counted drain: wait only W(k)'s 4 (oldest); W(k+1) stays in flight.
        if (kk < 7) asm volatile("s_waitcnt vmcnt(4)" ::: "memory");
        else        asm volatile("s_waitcnt vmcnt(0)" ::: "memory");
        __builtin_amdgcn_s_barrier();
        #pragma unroll
        for (int j = 0; j < 16; ++j) {    // one B-frag live at a time
            uint4 bfr = *(const uint4*)((const char*)Bs[cur] + (j * 16 + fr) * 64 + swoff);
            acc[0][j] = __builtin_amdgcn_mfma_f32_16x16x32_bf16(
                __builtin_bit_cast(bf16x8_t, afr0),
                __builtin_bit_cast(bf16x8_t, bfr), acc[0][j], 0, 0, 0);
            acc[1][j] = __builtin_amdgcn_mfma_f32_16x16x32_bf16(
                __builtin_bit_cast(bf16x8_t, afr1),
                __builtin_bit_cast(bf16x8_t, bfr), acc[1][j], 0, 0, 0);
        }
    }

    // epilogue: res[row][o] = sum_t escT[t][row] * acc — float4 escT reads.
    // frag j covers t = j>>1, channel = ogp*32 + (j&1)*16 + fr.
    const int oo = lane & 15;
    unsigned short* dst = He2 + (size_t)kh * 524288
                              + (size_t)(b * 1024 + n0) * 64 + ogp * 32;
    #pragma unroll
    for (int i = 0; i < 2; ++i) {
        const int rb = row_base + i * 16 + quad * 4;
        float s0[4] = {0.f, 0.f, 0.f, 0.f}, s1[4] = {0.f, 0.f, 0.f, 0.f};
        #pragma unroll
        for (int t = 0; t < 8; ++t) {
            const float4 ev = *(const float4*)&escT[t * 128 + rb];
            s0[0] += ev.x * acc[i][2 * t][0]; s1[0] += ev.x * acc[i][2 * t + 1][0];
            s0[1] += ev.y * acc[i][2 * t][1]; s1[1] += ev.y * acc[i][2 * t + 1][1];
            s0[2] += ev.z * acc[i][2 * t][2]; s1[2] += ev.z * acc[i][2 * t + 1][2];
            s0[3] += ev.w * acc[i][2 * t][3]; s1[3] += ev.w * acc[i][2 * t + 1][3];
        }
        #pragma unroll
        for (int r = 0; r < 4; ++r) {
            dst[(size_t)(rb + r) * 64 + oo] = f2bf(s0[r]);
            dst[(size_t)(rb + r) * 64 + 16 + oo] = f2bf(s1[r]);
        }
    }
}

// K4: out = sum of 4 bf16 He2 partials; fused BN sum/sumsq.
// XCD-matched remap: data-b == blockIdx&7 == XCD (same swizzle as producers).
__global__ __launch_bounds__(256) void k_fin(const unsigned short* __restrict__ He2,
                                             float* __restrict__ out,
                                             float* __restrict__ bns) {
    __shared__ float s1[16][64], s2[16][64];
    const int tid = threadIdx.x;
    const int vb = ((blockIdx.x & 7) << 5) | (blockIdx.x >> 3);  // bijective
    float a0 = 0.f, a1 = 0.f, a2 = 0.f, a3 = 0.f;
    float q0 = 0.f, q1 = 0.f, q2 = 0.f, q3 = 0.f;
    #pragma unroll
    for (int it = 0; it < 2; ++it) {
        const size_t idx = (size_t)vb * 512 + it * 256 + tid;    // ushort4 group
        float4 s = make_float4(0.f, 0.f, 0.f, 0.f);
        #pragma unroll
        for (int p = 0; p < 4; ++p) {
            ushort4 u = *(const ushort4*)(He2 + (size_t)p * 524288 + idx * 4);
            s.x += bf2f(u.x); s.y += bf2f(u.y); s.z += bf2f(u.z); s.w += bf2f(u.w);
        }
        ((float4*)out)[idx] = s;
        a0 += s.x; a1 += s.y; a2 += s.z; a3 += s.w;
        q0 += s.x * s.x; q1 += s.y * s.y; q2 += s.z * s.z; q3 += s.w * s.w;
    }
    const int g = tid >> 4, o4 = (tid & 15) * 4;
    *(float4*)&s1[g][o4] = make_float4(a0, a1, a2, a3);
    *(float4*)&s2[g][o4] = make_float4(q0, q1, q2, q3);
    __syncthreads();
    if (tid < 64) {
        float sa = 0.f, sb = 0.f;
        #pragma unroll
        for (int r = 0; r < 16; ++r) { sa += s1[r][tid]; sb += s2[r][tid]; }
        atomicAdd(&bns[tid], sa);
        atomicAdd(&bns[64 + tid], sb);
    }
}

// K5: in-place BN (training stats) + ReLU. XCD-matched remap like k_fin.
__global__ __launch_bounds__(256) void k_bn(float* __restrict__ out,
                                            const float* __restrict__ bns,
                                            const float* __restrict__ gamma,
                                            const float* __restrict__ beta) {
    const int vb = ((blockIdx.x & 7) << 6) | (blockIdx.x >> 3);  // bijective
    const int i = vb * 256 + threadIdx.x;
    const int o4 = (i & 15) * 4;
    float4 x = ((float4*)out)[i];
    const float4 s  = *(const float4*)&bns[o4];
    const float4 s2 = *(const float4*)&bns[64 + o4];
    const float4 gm = *(const float4*)&gamma[o4];
    const float4 bt = *(const float4*)&beta[o4];
    const float invn = 1.f / 8192.f;
    float m, v, w;
    m = s.x * invn; v = s2.x * invn - m * m; w = __frsqrt_rn(v + BN_EPS) * gm.x;
    x.x = fmaxf((x.x - m) * w + bt.x, 0.f);
    m = s.y * invn; v = s2.y * invn - m * m; w = __frsqrt_rn(v + BN_EPS) * gm.y;
    x.y = fmaxf((x.y - m) * w + bt.y, 0.f);
    m = s.z * invn; v = s2.z * invn - m * m; w = __frsqrt_rn(v + BN_EPS) * gm.z;
    x.z = fmaxf((x.z - m) * w + bt.z, 0.f);
    m = s.w * invn; v = s2.w * invn - m * m; w = __frsqrt_rn(v + BN_EPS) * gm.w;
    x.w = fmaxf((x.w - m) * w + bt.w, 0.f);
    ((float4*)out)[i] = x;
}

extern "C" void kernel_launch(void* const* d_in, const int* in_sizes, int n_in,
                              void* d_out, int out_size, void* d_ws, size_t ws_size,
                              hipStream_t stream) {
    const float* points = (const float*)d_in[0];
    const float* trans  = (const float*)d_in[1];
    const float* funcs  = (const float*)d_in[2];
    const float* ktens  = (const float*)d_in[3];
    const float* gamma  = (const float*)d_in[4];
    const float* beta   = (const float*)d_in[5];
    float* out = (float*)d_out;

    float* ws      = (float*)d_ws;
    float* escale  = ws;                    // 65536 f
    float* bns     = escale + 65536;        // 128 f
    float* rowsum  = bns + 128;             // 8192 f
    unsigned short* He2   = (unsigned short*)(rowsum + 8192);   // 2097152 us (4 MB)
    unsigned short* bmatT = He2 + 2097152;                      // 4194304 us (8 MB)

    k_gp<<<768, 256, 0, stream>>>(points, trans, funcs, ktens,
                                  rowsum, bmatT, escale, bns);
    k_gemm<<<512, 256, 0, stream>>>(points, bmatT, escale, rowsum, He2);
    k_fin<<<256, 256, 0, stream>>>(He2, out, bns);
    k_bn<<<512, 256, 0, stream>>>(out, bns, gamma, beta);
}